// Round 4
// baseline (2371.147 us; speedup 1.0000x reference)
//
#include <hip/hip_runtime.h>
#include <hip/hip_bf16.h>

#define BD 2
#define HD 480
#define WD 480
#define CD 32
#define HALFD 16
#define WND 20
#define NP 500
#define PLANE (HD*WD)
#define TWO_PI_OVER_NP 0.012566370614359172954f  /* 2*pi/500 */

__device__ __forceinline__ float gelu_f(float x) {
    return 0.5f * x * (1.0f + erff(x * 0.70710678118654752f));
}

// Input MLP for a: MLP 5->16->32 on (src, grid). Channel-planar bf16 (B,C,H,W).
__global__ void __launch_bounds__(256) k_ae(
    const float* src,
    const float* iw1, const float* ib1,
    const float* iw2, const float* ib2,
    __hip_bfloat16* A)
{
    __shared__ float s_iw1[80], s_ib1[16], s_iw2[512], s_ib2[32];
    int tid = threadIdx.x;
    for (int t = tid; t < 512; t += 256) s_iw2[t] = iw2[t];
    if (tid < 80) s_iw1[tid] = iw1[tid];
    if (tid >= 96 && tid < 112) s_ib1[tid - 96] = ib1[tid - 96];
    if (tid >= 128 && tid < 160) s_ib2[tid - 128] = ib2[tid - 128];
    __syncthreads();
    int gid = blockIdx.x * 256 + tid;  // < 460800
    int b = gid / PLANE;
    int r = gid % PLANE;
    int h = r / WD, w = r % WD;
    float gx = (float)h * (1.0f / 479.0f);
    float gy = (float)w * (1.0f / 479.0f);
    float s0 = src[(size_t)gid * 3 + 0];
    float s1 = src[(size_t)gid * 3 + 1];
    float s2 = src[(size_t)gid * 3 + 2];
    float hid[16];
    #pragma unroll
    for (int j = 0; j < 16; j++) {
        float v = s_ib1[j] + s0 * s_iw1[j] + s1 * s_iw1[16 + j] + s2 * s_iw1[32 + j]
                + gx * s_iw1[48 + j] + gy * s_iw1[64 + j];
        hid[j] = gelu_f(v);
    }
    __hip_bfloat16* Ap = A + (size_t)b * CD * PLANE + r;
    for (int c = 0; c < 32; c++) {
        float v = s_ib2[c];
        #pragma unroll
        for (int j = 0; j < 16; j++) v += hid[j] * s_iw2[j * 32 + c];
        Ap[(size_t)c * PLANE] = __float2bfloat16(v);
    }
}

// F1: one block per (b,h) row. Recomputes e on the fly (MLP 3->16->32 from
// input+grid), forms g = a*e in LDS (16 channels per pass), then DFT over w
// for ky=0..19. Y1[bc][ky][h] complex bf16.
__global__ void __launch_bounds__(256) k_F1g(
    const __hip_bfloat16* A, const float* inp,
    const float* ew1, const float* eb1,
    const float* ew2, const float* eb2,
    __hip_bfloat16* Y1)
{
    __shared__ float sC[NP], sS[NP];
    __shared__ float sG[16 * 481];
    __shared__ float s_ew1[48], s_eb1[16], s_ew2[512], s_eb2[32];
    int tid = threadIdx.x;
    for (int t = tid; t < NP; t += 256) {
        float ang = (float)t * TWO_PI_OVER_NP;
        sC[t] = cosf(ang);
        sS[t] = sinf(ang);
    }
    for (int t = tid; t < 512; t += 256) s_ew2[t] = ew2[t];
    if (tid < 48) s_ew1[tid] = ew1[tid];
    if (tid >= 64 && tid < 80) s_eb1[tid - 64] = eb1[tid - 64];
    if (tid >= 96 && tid < 128) s_eb2[tid - 96] = eb2[tid - 96];
    __syncthreads();
    int b = blockIdx.x / HD;
    int h = blockIdx.x % HD;
    float gx = (float)h * (1.0f / 479.0f);
    const size_t rowoff = (size_t)h * WD;
    for (int half = 0; half < 2; half++) {
        int c0 = half * 16;
        for (int w = tid; w < WD; w += 256) {
            float xi = inp[(size_t)b * PLANE + rowoff + w];
            float gy = (float)w * (1.0f / 479.0f);
            float hid[16];
            #pragma unroll
            for (int j = 0; j < 16; j++) {
                float v = s_eb1[j] + xi * s_ew1[j] + gx * s_ew1[16 + j] + gy * s_ew1[32 + j];
                hid[j] = gelu_f(v);
            }
            #pragma unroll
            for (int cc = 0; cc < 16; cc++) {
                int c = c0 + cc;
                float e = s_eb2[c];
                #pragma unroll
                for (int j = 0; j < 16; j++) e += hid[j] * s_ew2[j * 32 + c];
                float a = __bfloat162float(A[((size_t)(b * 32 + c)) * PLANE + rowoff + w]);
                sG[cc * 481 + w] = e * a;
            }
        }
        __syncthreads();
        for (int task = tid; task < 320; task += 256) {
            int cc = task / 20, ky = task % 20;
            int c = c0 + cc;
            const float* gp = sG + cc * 481;
            float ar = 0.f, ai = 0.f;
            int idx = 0;
            for (int w = 0; w < WD; w++) {
                float g = gp[w];
                ar += g * sC[idx];
                ai -= g * sS[idx];
                idx += ky; if (idx >= NP) idx -= NP;
            }
            __hip_bfloat162 v;
            v.x = __float2bfloat16(ar);
            v.y = __float2bfloat16(ai);
            reinterpret_cast<__hip_bfloat162*>(Y1)[((size_t)(b * 32 + c) * WND + ky) * HD + h] = v;
        }
        __syncthreads();
    }
}

// F2: DFT over h for the 40 needed kx. Y2[b,c,ky,kxi] complex fp32.
__global__ void __launch_bounds__(256) k_F2(
    const __hip_bfloat16* Y1, float* Y2)
{
    __shared__ float sC[NP], sS[NP];
    int tid = threadIdx.x;
    for (int t = tid; t < NP; t += 256) {
        float ang = (float)t * TWO_PI_OVER_NP;
        sC[t] = cosf(ang);
        sS[t] = sinf(ang);
    }
    __syncthreads();
    int gid = blockIdx.x * 256 + tid;   // < 51200
    int kxi = gid % 40;
    int ky = (gid / 40) % 20;
    int bc = gid / 800;
    int kx = (kxi < 20) ? kxi : kxi + 460;
    const __hip_bfloat162* y1 = reinterpret_cast<const __hip_bfloat162*>(Y1)
                                + (size_t)bc * WND * HD + (size_t)ky * HD;
    int idx = 0;
    float ar = 0.f, ai = 0.f;
    for (int hh = 0; hh < HD; hh++) {
        __hip_bfloat162 y = y1[hh];
        float yr = __bfloat162float(y.x), yi = __bfloat162float(y.y);
        float cv = sC[idx], sv = sS[idx];
        ar += yr * cv + yi * sv;
        ai += yi * cv - yr * sv;
        idx += kx;
        if (idx >= NP) idx -= NP;
    }
    reinterpret_cast<float2*>(Y2)[((size_t)bc * WND + ky) * 40 + kxi] = make_float2(ar, ai);
}

// Per-frequency channel mixing (real and imag independently).
__global__ void __launch_bounds__(256) k_mix(
    const float* Y2, float* Z,
    const float* fw1, const float* fw2, int l)
{
    int gid = blockIdx.x * 256 + threadIdx.x;  // < 102400
    int z = gid & 1;
    int kxi = (gid >> 1) % 40;
    int ky = (gid / 80) % 20;
    int oc = (gid / 1600) % 32;
    int b = gid / 51200;
    const float* wp;
    int x;
    if (kxi < 20) { wp = fw1; x = kxi; } else { wp = fw2; x = kxi - 20; }
    size_t wbase = ((((size_t)(l * 32) * 32 + oc) * 20 + x) * 20 + ky) * 2 + z;
    const float* y2 = Y2 + (((size_t)b * 32 * 20 + ky) * 40 + kxi) * 2 + z;
    float acc = 0.f;
    for (int i = 0; i < 32; i++) {
        float yv = y2[(size_t)i * 1600];
        float wv = wp[wbase + (size_t)i * 25600];
        acc += yv * wv;
    }
    Z[((((size_t)b * 32 + oc) * 20 + ky) * 40 + kxi) * 2 + z] = acc;
}

// I1: inverse complex DFT over kx -> h. U[b,o,ky,h] complex bf16 (unscaled).
__global__ void __launch_bounds__(256) k_I1(
    const float* Z, __hip_bfloat16* U)
{
    __shared__ float sC[NP], sS[NP];
    int tid = threadIdx.x;
    for (int t = tid; t < NP; t += 256) {
        float ang = (float)t * TWO_PI_OVER_NP;
        sC[t] = cosf(ang);
        sS[t] = sinf(ang);
    }
    __syncthreads();
    int gid = blockIdx.x * 256 + tid;  // < 614400
    int h = gid % HD;
    int ky = (gid / HD) % 20;
    int bo = gid / (HD * 20);   // b*32+oc
    const float2* zp = reinterpret_cast<const float2*>(Z) + ((size_t)bo * WND + ky) * 40;
    float ar = 0.f, ai = 0.f;
    int idx = 0;
    #pragma unroll
    for (int j = 0; j < 20; j++) {
        float2 zz = zp[j];
        float cv = sC[idx], sv = sS[idx];
        ar += zz.x * cv - zz.y * sv;
        ai += zz.x * sv + zz.y * cv;
        idx += h; if (idx >= NP) idx -= NP;
    }
    idx = (480 * h) % NP;
    #pragma unroll
    for (int j = 20; j < 40; j++) {
        float2 zz = zp[j];
        float cv = sC[idx], sv = sS[idx];
        ar += zz.x * cv - zz.y * sv;
        ai += zz.x * sv + zz.y * cv;
        idx += h; if (idx >= NP) idx -= NP;
    }
    __hip_bfloat162 v;
    v.x = __float2bfloat16(ar);
    v.y = __float2bfloat16(ai);
    reinterpret_cast<__hip_bfloat162*>(U)[((size_t)bo * WND + ky) * HD + h] = v;
}

// I2: inverse DFT over ky -> w fused with 1x1 conv, bias, gelu. IN-PLACE on A:
// each thread owns pixels (h, w) exclusively.
__global__ void __launch_bounds__(256) k_I2(
    const __hip_bfloat16* U, __hip_bfloat16* A,
    const float* convw, const float* convb,
    int l, int do_gelu)
{
    __shared__ float sC[NP], sS[NP];
    __shared__ float sU[CD * WND * 2];
    __shared__ float sW[CD * CD];
    __shared__ float sB[CD];
    int tid = threadIdx.x;
    for (int t = tid; t < NP; t += 256) {
        float ang = (float)t * TWO_PI_OVER_NP;
        sC[t] = cosf(ang);
        sS[t] = sinf(ang);
    }
    int b = blockIdx.x / HD;
    int h = blockIdx.x % HD;
    for (int t = tid; t < CD * WND; t += 256) {
        int oc = t / WND, ky = t % WND;
        __hip_bfloat162 u = reinterpret_cast<const __hip_bfloat162*>(U)
                                [(((size_t)b * CD + oc) * WND + ky) * HD + h];
        float sc = (ky == 0 ? 1.0f : 2.0f) * (1.0f / 250000.0f);
        sU[t * 2] = __bfloat162float(u.x) * sc;
        sU[t * 2 + 1] = __bfloat162float(u.y) * sc;
    }
    for (int t = tid; t < CD * CD; t += 256) sW[t] = convw[(size_t)l * CD * CD + t];
    if (tid < CD) sB[tid] = convb[(size_t)l * CD + tid];
    __syncthreads();
    for (int w = tid; w < WD; w += 256) {
        float av[32];
        __hip_bfloat16* ap = A + (size_t)b * CD * PLANE + (size_t)h * WD + w;
        #pragma unroll
        for (int i = 0; i < 32; i++) av[i] = __bfloat162float(ap[(size_t)i * PLANE]);
        float tc[20], ts[20];
        int idx = 0;
        #pragma unroll
        for (int ky = 0; ky < 20; ky++) {
            tc[ky] = sC[idx]; ts[ky] = sS[idx];
            idx += w; if (idx >= NP) idx -= NP;
        }
        #pragma unroll
        for (int oc = 0; oc < 32; oc++) {
            float acc = sB[oc];
            const float* up = sU + oc * 40;
            #pragma unroll
            for (int ky = 0; ky < 20; ky++)
                acc += up[ky * 2] * tc[ky] - up[ky * 2 + 1] * ts[ky];
            const float* wp2 = sW + oc * 32;
            #pragma unroll
            for (int i = 0; i < 32; i++) acc += av[i] * wp2[i];
            if (do_gelu) acc = gelu_f(acc);
            ap[(size_t)oc * PLANE] = __float2bfloat16(acc);
        }
    }
}

// Final: proj MLP + 3x3 mask conv (XLA conv = correlation) + field*mask + pred.
__global__ void __launch_bounds__(256) k_out(
    const __hip_bfloat16* Afin, const float* inp, const float* src,
    const float* pw1, const float* pb1,
    const float* pw2, const float* pb2,
    const float* mw, const float* mb,
    float* out)
{
    __shared__ float sW1[CD * HALFD], sB1[HALFD], sW2[HALFD * 2], sB2[2], sM[9], sMB[1];
    int tid = threadIdx.x;
    for (int t = tid; t < CD * HALFD; t += 256) sW1[t] = pw1[t];
    if (tid < 16) sB1[tid] = pb1[tid];
    if (tid >= 32 && tid < 64) sW2[tid - 32] = pw2[tid - 32];
    if (tid >= 64 && tid < 66) sB2[tid - 64] = pb2[tid - 64];
    if (tid >= 96 && tid < 105) sM[tid - 96] = mw[tid - 96];
    if (tid == 128) sMB[0] = mb[0];
    __syncthreads();
    int gid = blockIdx.x * 256 + tid;  // < 460800
    int b = gid / PLANE;
    int r = gid % PLANE;
    int h = r / WD, w = r % WD;
    const __hip_bfloat16* ap = Afin + (size_t)b * CD * PLANE + r;
    float av[32];
    #pragma unroll
    for (int i = 0; i < 32; i++) av[i] = __bfloat162float(ap[(size_t)i * PLANE]);
    float hid[16];
    #pragma unroll
    for (int j = 0; j < 16; j++) {
        float v = sB1[j];
        #pragma unroll
        for (int i = 0; i < 32; i++) v += av[i] * sW1[i * 16 + j];
        hid[j] = gelu_f(v);
    }
    float p0 = sB2[0], p1 = sB2[1];
    #pragma unroll
    for (int j = 0; j < 16; j++) { p0 += hid[j] * sW2[j * 2]; p1 += hid[j] * sW2[j * 2 + 1]; }
    float m = sMB[0];
    #pragma unroll
    for (int dh = 0; dh < 3; dh++) {
        int hh = h + dh - 1;
        #pragma unroll
        for (int dw = 0; dw < 3; dw++) {
            int ww = w + dw - 1;
            if (hh >= 0 && hh < HD && ww >= 0 && ww < WD)
                m += inp[(size_t)b * PLANE + (size_t)hh * WD + ww] * sM[dh * 3 + dw];
        }
    }
    float f0 = src[(size_t)gid * 3 + 1];
    float f1 = src[(size_t)gid * 3 + 2];
    out[(size_t)gid * 2 + 0] = f0 * m + p0;
    out[(size_t)gid * 2 + 1] = f1 * m + p1;
}

extern "C" void kernel_launch(void* const* d_in, const int* in_sizes, int n_in,
                              void* d_out, int out_size, void* d_ws, size_t ws_size,
                              hipStream_t stream) {
    // All reference dtypes are float32 (rounds 1-3 read them as bf16 -> the
    // low-half-of-float garbage exponents explain the persistent NaN).
    const float* inp = (const float*)d_in[0];
    const float* src = (const float*)d_in[1];
    const float* iw1 = (const float*)d_in[2];
    const float* ib1 = (const float*)d_in[3];
    const float* iw2 = (const float*)d_in[4];
    const float* ib2 = (const float*)d_in[5];
    const float* ew1 = (const float*)d_in[6];
    const float* eb1 = (const float*)d_in[7];
    const float* ew2 = (const float*)d_in[8];
    const float* eb2 = (const float*)d_in[9];
    const float* fw1 = (const float*)d_in[10];
    const float* fw2 = (const float*)d_in[11];
    const float* cw  = (const float*)d_in[12];
    const float* cb  = (const float*)d_in[13];
    const float* pw1 = (const float*)d_in[14];
    const float* pb1 = (const float*)d_in[15];
    const float* pw2 = (const float*)d_in[16];
    const float* pb2 = (const float*)d_in[17];
    const float* mw  = (const float*)d_in[18];
    const float* mb  = (const float*)d_in[19];

    // Workspace layout — total 32,768,000 B = 31.25 MiB:
    //   A    bf16  [64][480][480]        29,491,200 B   layer state, in-place
    //   Y1U  bf16  [64][20][480]x2        2,457,600 B   Y1 (F1->F2) aliased with U (I1->I2)
    //   Y2   fp32  [64][20][40]x2           409,600 B
    //   Z    fp32  [64][20][40]x2           409,600 B
    const size_t NA = (size_t)BD * CD * PLANE;          // 14,745,600 elems
    __hip_bfloat16* A   = (__hip_bfloat16*)d_ws;
    __hip_bfloat16* Y1U = A + NA;
    float* Y2 = (float*)(Y1U + (size_t)BD * CD * WND * HD * 2);
    float* Z  = Y2 + (size_t)BD * CD * WND * 40 * 2;

    k_ae<<<1800, 256, 0, stream>>>(src, iw1, ib1, iw2, ib2, A);

    for (int l = 0; l < 4; l++) {
        k_F1g<<<BD * HD, 256, 0, stream>>>(A, inp, ew1, eb1, ew2, eb2, Y1U);
        k_F2<<<200, 256, 0, stream>>>(Y1U, Y2);
        k_mix<<<400, 256, 0, stream>>>(Y2, Z, fw1, fw2, l);
        k_I1<<<2400, 256, 0, stream>>>(Z, Y1U);
        k_I2<<<BD * HD, 256, 0, stream>>>(Y1U, A, cw, cb, l, (l < 3) ? 1 : 0);
    }
    k_out<<<1800, 256, 0, stream>>>(A, inp, src, pw1, pb1, pw2, pb2, mw, mb,
                                    (float*)d_out);
}

// Round 5
// 1408.019 us; speedup vs baseline: 1.6840x; 1.6840x over previous
//
#include <hip/hip_runtime.h>
#include <hip/hip_bf16.h>

#define BD 2
#define HD 480
#define WD 480
#define CD 32
#define HALFD 16
#define WND 20
#define NP 500
#define PLANE (HD*WD)
#define TWO_PI_OVER_NP 0.012566370614359172954f  /* 2*pi/500 */

typedef __attribute__((ext_vector_type(8))) short bf16x8;
typedef __attribute__((ext_vector_type(4))) float f32x4;

__device__ __forceinline__ float gelu_f(float x) {
    return 0.5f * x * (1.0f + erff(x * 0.70710678118654752f));
}

// Input MLP for a: MLP 5->16->32 on (src, grid). Channel-planar bf16 (B,C,H,W).
__global__ void __launch_bounds__(256) k_ae(
    const float* src,
    const float* iw1, const float* ib1,
    const float* iw2, const float* ib2,
    __hip_bfloat16* A)
{
    __shared__ float s_iw1[80], s_ib1[16], s_iw2[512], s_ib2[32];
    int tid = threadIdx.x;
    for (int t = tid; t < 512; t += 256) s_iw2[t] = iw2[t];
    if (tid < 80) s_iw1[tid] = iw1[tid];
    if (tid >= 96 && tid < 112) s_ib1[tid - 96] = ib1[tid - 96];
    if (tid >= 128 && tid < 160) s_ib2[tid - 128] = ib2[tid - 128];
    __syncthreads();
    int gid = blockIdx.x * 256 + tid;  // < 460800
    int b = gid / PLANE;
    int r = gid % PLANE;
    int h = r / WD, w = r % WD;
    float gx = (float)h * (1.0f / 479.0f);
    float gy = (float)w * (1.0f / 479.0f);
    float s0 = src[(size_t)gid * 3 + 0];
    float s1 = src[(size_t)gid * 3 + 1];
    float s2 = src[(size_t)gid * 3 + 2];
    float hid[16];
    #pragma unroll
    for (int j = 0; j < 16; j++) {
        float v = s_ib1[j] + s0 * s_iw1[j] + s1 * s_iw1[16 + j] + s2 * s_iw1[32 + j]
                + gx * s_iw1[48 + j] + gy * s_iw1[64 + j];
        hid[j] = gelu_f(v);
    }
    __hip_bfloat16* Ap = A + (size_t)b * CD * PLANE + r;
    for (int c = 0; c < 32; c++) {
        float v = s_ib2[c];
        #pragma unroll
        for (int j = 0; j < 16; j++) v += hid[j] * s_iw2[j * 32 + c];
        Ap[(size_t)c * PLANE] = __float2bfloat16(v);
    }
}

// Precompute swizzled bf16 twiddle fragments for the F1 row-DFT GEMM.
// B[k=w][n], n = ky*2+part (part0=cos, part1=-sin), n in [0,40) (pad to 48).
// Tile (kt 0..14, nt 0..2): 64 lanes x 8 elems contiguous; element (lane,j)
// holds B[kt*32 + (lane>>4)*8 + j][nt*16 + (lane&15)].
__global__ void k_twig(__hip_bfloat16* Twig) {
    int e = blockIdx.x * 256 + threadIdx.x;   // < 45*512 = 23040
    if (e >= 45 * 512) return;
    int tile = e >> 9, r = e & 511;
    int lane = r >> 3, j = r & 7;
    int kt = tile / 3, nt = tile % 3;
    int k = kt * 32 + ((lane >> 4) << 3) + j;
    int n = nt * 16 + (lane & 15);
    float v = 0.0f;
    if (n < 40) {
        int ky = n >> 1;
        int idx = (k * ky) % NP;
        float ang = (float)idx * TWO_PI_OVER_NP;
        v = (n & 1) ? -sinf(ang) : cosf(ang);
    }
    Twig[e] = __float2bfloat16(v);
}

// F1: one block per (b,h) row. Phase 1: recompute e-MLP once per pixel and
// stage g = a*e as bf16 in LDS G[32][488]. Phase 2: row-DFT over w as MFMA
// GEMM (M=32 c, N=48 ky-part padded, K=480 w) against swizzled Twig.
__global__ void __launch_bounds__(256) k_F1g(
    const __hip_bfloat16* A, const float* inp,
    const float* ew1, const float* eb1,
    const float* ew2, const float* eb2,
    const __hip_bfloat16* Twig,
    __hip_bfloat16* Y1)
{
    __shared__ __hip_bfloat16 G[32][488];   // pitch 488: 2-way bank aliasing only
    __shared__ float s_ew1[48], s_eb1[16], s_ew2[512], s_eb2[32];
    int tid = threadIdx.x;
    for (int t = tid; t < 512; t += 256) s_ew2[t] = ew2[t];
    if (tid < 48) s_ew1[tid] = ew1[tid];
    if (tid >= 64 && tid < 80) s_eb1[tid - 64] = eb1[tid - 64];
    if (tid >= 96 && tid < 128) s_eb2[tid - 96] = eb2[tid - 96];
    __syncthreads();
    int b = blockIdx.x / HD;
    int h = blockIdx.x % HD;
    float gx = (float)h * (1.0f / 479.0f);
    const __hip_bfloat16* Abase = A + ((size_t)b * CD) * PLANE + (size_t)h * WD;
    // phase 1: g = a * e, all 32 channels, one e-MLP eval per pixel
    for (int w = tid; w < WD; w += 256) {
        float xi = inp[(size_t)b * PLANE + (size_t)h * WD + w];
        float gy = (float)w * (1.0f / 479.0f);
        float hid[16];
        #pragma unroll
        for (int j = 0; j < 16; j++) {
            float v = s_eb1[j] + xi * s_ew1[j] + gx * s_ew1[16 + j] + gy * s_ew1[32 + j];
            hid[j] = gelu_f(v);
        }
        #pragma unroll
        for (int c = 0; c < 32; c++) {
            float e = s_eb2[c];
            #pragma unroll
            for (int j = 0; j < 16; j++) e += hid[j] * s_ew2[j * 32 + c];
            float a = __bfloat162float(Abase[(size_t)c * PLANE + w]);
            G[c][w] = __float2bfloat16(e * a);
        }
    }
    __syncthreads();
    // phase 2: D[c][n] = sum_w G[c][w] * T[w][n]; 6 tiles over 4 waves
    int wv = tid >> 6, lane = tid & 63;
    int arow_lo = lane & 15;
    int kofs = (lane >> 4) << 3;
    for (int t = wv; t < 6; t += 4) {
        int mt = t & 1, nt = t >> 1;
        f32x4 acc = {0.f, 0.f, 0.f, 0.f};
        int arow = mt * 16 + arow_lo;
        #pragma unroll
        for (int kt = 0; kt < 15; kt++) {
            bf16x8 av = *reinterpret_cast<const bf16x8*>(&G[arow][kt * 32 + kofs]);
            bf16x8 bv = *reinterpret_cast<const bf16x8*>(Twig + (((kt * 3 + nt) << 9) + lane * 8));
            acc = __builtin_amdgcn_mfma_f32_16x16x32_bf16(av, bv, acc, 0, 0, 0);
        }
        int n = nt * 16 + (lane & 15);
        if (n < 40) {
            int ky = n >> 1, part = n & 1;
            int crow = mt * 16 + ((lane >> 4) << 2);
            #pragma unroll
            for (int r = 0; r < 4; r++) {
                int c = crow + r;
                Y1[((((size_t)(b * 32 + c)) * WND + ky) * HD + h) * 2 + part] =
                    __float2bfloat16(acc[r]);
            }
        }
    }
}

// F2: DFT over h for the 40 needed kx. Y2[b,c,ky,kxi] complex fp32.
__global__ void __launch_bounds__(256) k_F2(
    const __hip_bfloat16* Y1, float* Y2)
{
    __shared__ float sC[NP], sS[NP];
    int tid = threadIdx.x;
    for (int t = tid; t < NP; t += 256) {
        float ang = (float)t * TWO_PI_OVER_NP;
        sC[t] = cosf(ang);
        sS[t] = sinf(ang);
    }
    __syncthreads();
    int gid = blockIdx.x * 256 + tid;   // < 51200
    int kxi = gid % 40;
    int ky = (gid / 40) % 20;
    int bc = gid / 800;
    int kx = (kxi < 20) ? kxi : kxi + 460;
    const __hip_bfloat162* y1 = reinterpret_cast<const __hip_bfloat162*>(Y1)
                                + (size_t)bc * WND * HD + (size_t)ky * HD;
    int idx = 0;
    float ar = 0.f, ai = 0.f;
    for (int hh = 0; hh < HD; hh++) {
        __hip_bfloat162 y = y1[hh];
        float yr = __bfloat162float(y.x), yi = __bfloat162float(y.y);
        float cv = sC[idx], sv = sS[idx];
        ar += yr * cv + yi * sv;
        ai += yi * cv - yr * sv;
        idx += kx;
        if (idx >= NP) idx -= NP;
    }
    reinterpret_cast<float2*>(Y2)[((size_t)bc * WND + ky) * 40 + kxi] = make_float2(ar, ai);
}

// Per-frequency channel mixing (real and imag independently).
__global__ void __launch_bounds__(256) k_mix(
    const float* Y2, float* Z,
    const float* fw1, const float* fw2, int l)
{
    int gid = blockIdx.x * 256 + threadIdx.x;  // < 102400
    int z = gid & 1;
    int kxi = (gid >> 1) % 40;
    int ky = (gid / 80) % 20;
    int oc = (gid / 1600) % 32;
    int b = gid / 51200;
    const float* wp;
    int x;
    if (kxi < 20) { wp = fw1; x = kxi; } else { wp = fw2; x = kxi - 20; }
    size_t wbase = ((((size_t)(l * 32) * 32 + oc) * 20 + x) * 20 + ky) * 2 + z;
    const float* y2 = Y2 + (((size_t)b * 32 * 20 + ky) * 40 + kxi) * 2 + z;
    float acc = 0.f;
    for (int i = 0; i < 32; i++) {
        float yv = y2[(size_t)i * 1600];
        float wv = wp[wbase + (size_t)i * 25600];
        acc += yv * wv;
    }
    Z[((((size_t)b * 32 + oc) * 20 + ky) * 40 + kxi) * 2 + z] = acc;
}

// I1: inverse complex DFT over kx -> h. U[b,o,ky,h] complex bf16 (unscaled).
__global__ void __launch_bounds__(256) k_I1(
    const float* Z, __hip_bfloat16* U)
{
    __shared__ float sC[NP], sS[NP];
    int tid = threadIdx.x;
    for (int t = tid; t < NP; t += 256) {
        float ang = (float)t * TWO_PI_OVER_NP;
        sC[t] = cosf(ang);
        sS[t] = sinf(ang);
    }
    __syncthreads();
    int gid = blockIdx.x * 256 + tid;  // < 614400
    int h = gid % HD;
    int ky = (gid / HD) % 20;
    int bo = gid / (HD * 20);   // b*32+oc
    const float2* zp = reinterpret_cast<const float2*>(Z) + ((size_t)bo * WND + ky) * 40;
    float ar = 0.f, ai = 0.f;
    int idx = 0;
    #pragma unroll
    for (int j = 0; j < 20; j++) {
        float2 zz = zp[j];
        float cv = sC[idx], sv = sS[idx];
        ar += zz.x * cv - zz.y * sv;
        ai += zz.x * sv + zz.y * cv;
        idx += h; if (idx >= NP) idx -= NP;
    }
    idx = (480 * h) % NP;
    #pragma unroll
    for (int j = 20; j < 40; j++) {
        float2 zz = zp[j];
        float cv = sC[idx], sv = sS[idx];
        ar += zz.x * cv - zz.y * sv;
        ai += zz.x * sv + zz.y * cv;
        idx += h; if (idx >= NP) idx -= NP;
    }
    __hip_bfloat162 v;
    v.x = __float2bfloat16(ar);
    v.y = __float2bfloat16(ai);
    reinterpret_cast<__hip_bfloat162*>(U)[((size_t)bo * WND + ky) * HD + h] = v;
}

// I2: inverse DFT over ky -> w fused with 1x1 conv, bias, gelu. IN-PLACE on A:
// each thread owns pixels (h, w) exclusively.
__global__ void __launch_bounds__(256) k_I2(
    const __hip_bfloat16* U, __hip_bfloat16* A,
    const float* convw, const float* convb,
    int l, int do_gelu)
{
    __shared__ float sC[NP], sS[NP];
    __shared__ float sU[CD * WND * 2];
    __shared__ float sW[CD * CD];
    __shared__ float sB[CD];
    int tid = threadIdx.x;
    for (int t = tid; t < NP; t += 256) {
        float ang = (float)t * TWO_PI_OVER_NP;
        sC[t] = cosf(ang);
        sS[t] = sinf(ang);
    }
    int b = blockIdx.x / HD;
    int h = blockIdx.x % HD;
    for (int t = tid; t < CD * WND; t += 256) {
        int oc = t / WND, ky = t % WND;
        __hip_bfloat162 u = reinterpret_cast<const __hip_bfloat162*>(U)
                                [(((size_t)b * CD + oc) * WND + ky) * HD + h];
        float sc = (ky == 0 ? 1.0f : 2.0f) * (1.0f / 250000.0f);
        sU[t * 2] = __bfloat162float(u.x) * sc;
        sU[t * 2 + 1] = __bfloat162float(u.y) * sc;
    }
    for (int t = tid; t < CD * CD; t += 256) sW[t] = convw[(size_t)l * CD * CD + t];
    if (tid < CD) sB[tid] = convb[(size_t)l * CD + tid];
    __syncthreads();
    for (int w = tid; w < WD; w += 256) {
        float av[32];
        __hip_bfloat16* ap = A + (size_t)b * CD * PLANE + (size_t)h * WD + w;
        #pragma unroll
        for (int i = 0; i < 32; i++) av[i] = __bfloat162float(ap[(size_t)i * PLANE]);
        float tc[20], ts[20];
        int idx = 0;
        #pragma unroll
        for (int ky = 0; ky < 20; ky++) {
            tc[ky] = sC[idx]; ts[ky] = sS[idx];
            idx += w; if (idx >= NP) idx -= NP;
        }
        #pragma unroll
        for (int oc = 0; oc < 32; oc++) {
            float acc = sB[oc];
            const float* up = sU + oc * 40;
            #pragma unroll
            for (int ky = 0; ky < 20; ky++)
                acc += up[ky * 2] * tc[ky] - up[ky * 2 + 1] * ts[ky];
            const float* wp2 = sW + oc * 32;
            #pragma unroll
            for (int i = 0; i < 32; i++) acc += av[i] * wp2[i];
            if (do_gelu) acc = gelu_f(acc);
            ap[(size_t)oc * PLANE] = __float2bfloat16(acc);
        }
    }
}

// Final: proj MLP + 3x3 mask conv (XLA conv = correlation) + field*mask + pred.
__global__ void __launch_bounds__(256) k_out(
    const __hip_bfloat16* Afin, const float* inp, const float* src,
    const float* pw1, const float* pb1,
    const float* pw2, const float* pb2,
    const float* mw, const float* mb,
    float* out)
{
    __shared__ float sW1[CD * HALFD], sB1[HALFD], sW2[HALFD * 2], sB2[2], sM[9], sMB[1];
    int tid = threadIdx.x;
    for (int t = tid; t < CD * HALFD; t += 256) sW1[t] = pw1[t];
    if (tid < 16) sB1[tid] = pb1[tid];
    if (tid >= 32 && tid < 64) sW2[tid - 32] = pw2[tid - 32];
    if (tid >= 64 && tid < 66) sB2[tid - 64] = pb2[tid - 64];
    if (tid >= 96 && tid < 105) sM[tid - 96] = mw[tid - 96];
    if (tid == 128) sMB[0] = mb[0];
    __syncthreads();
    int gid = blockIdx.x * 256 + tid;  // < 460800
    int b = gid / PLANE;
    int r = gid % PLANE;
    int h = r / WD, w = r % WD;
    const __hip_bfloat16* ap = Afin + (size_t)b * CD * PLANE + r;
    float av[32];
    #pragma unroll
    for (int i = 0; i < 32; i++) av[i] = __bfloat162float(ap[(size_t)i * PLANE]);
    float hid[16];
    #pragma unroll
    for (int j = 0; j < 16; j++) {
        float v = sB1[j];
        #pragma unroll
        for (int i = 0; i < 32; i++) v += av[i] * sW1[i * 16 + j];
        hid[j] = gelu_f(v);
    }
    float p0 = sB2[0], p1 = sB2[1];
    #pragma unroll
    for (int j = 0; j < 16; j++) { p0 += hid[j] * sW2[j * 2]; p1 += hid[j] * sW2[j * 2 + 1]; }
    float m = sMB[0];
    #pragma unroll
    for (int dh = 0; dh < 3; dh++) {
        int hh = h + dh - 1;
        #pragma unroll
        for (int dw = 0; dw < 3; dw++) {
            int ww = w + dw - 1;
            if (hh >= 0 && hh < HD && ww >= 0 && ww < WD)
                m += inp[(size_t)b * PLANE + (size_t)hh * WD + ww] * sM[dh * 3 + dw];
        }
    }
    float f0 = src[(size_t)gid * 3 + 1];
    float f1 = src[(size_t)gid * 3 + 2];
    out[(size_t)gid * 2 + 0] = f0 * m + p0;
    out[(size_t)gid * 2 + 1] = f1 * m + p1;
}

extern "C" void kernel_launch(void* const* d_in, const int* in_sizes, int n_in,
                              void* d_out, int out_size, void* d_ws, size_t ws_size,
                              hipStream_t stream) {
    const float* inp = (const float*)d_in[0];
    const float* src = (const float*)d_in[1];
    const float* iw1 = (const float*)d_in[2];
    const float* ib1 = (const float*)d_in[3];
    const float* iw2 = (const float*)d_in[4];
    const float* ib2 = (const float*)d_in[5];
    const float* ew1 = (const float*)d_in[6];
    const float* eb1 = (const float*)d_in[7];
    const float* ew2 = (const float*)d_in[8];
    const float* eb2 = (const float*)d_in[9];
    const float* fw1 = (const float*)d_in[10];
    const float* fw2 = (const float*)d_in[11];
    const float* cw  = (const float*)d_in[12];
    const float* cb  = (const float*)d_in[13];
    const float* pw1 = (const float*)d_in[14];
    const float* pb1 = (const float*)d_in[15];
    const float* pw2 = (const float*)d_in[16];
    const float* pb2 = (const float*)d_in[17];
    const float* mw  = (const float*)d_in[18];
    const float* mb  = (const float*)d_in[19];

    // Workspace layout — total ~31.3 MiB:
    //   A    bf16  [64][480][480]        29,491,200 B   layer state, in-place
    //   Y1U  bf16  [64][20][480]x2        2,457,600 B   Y1 (F1->F2) aliased with U (I1->I2)
    //   Y2   fp32  [64][20][40]x2           409,600 B
    //   Z    fp32  [64][20][40]x2           409,600 B
    //   Twig bf16  45 tiles x 512             46,080 B   swizzled DFT-1 B-fragments
    const size_t NA = (size_t)BD * CD * PLANE;          // 14,745,600 elems
    __hip_bfloat16* A   = (__hip_bfloat16*)d_ws;
    __hip_bfloat16* Y1U = A + NA;
    float* Y2 = (float*)(Y1U + (size_t)BD * CD * WND * HD * 2);
    float* Z  = Y2 + (size_t)BD * CD * WND * 40 * 2;
    __hip_bfloat16* Twig = (__hip_bfloat16*)(Z + (size_t)BD * CD * WND * 40 * 2);

    k_twig<<<90, 256, 0, stream>>>(Twig);
    k_ae<<<1800, 256, 0, stream>>>(src, iw1, ib1, iw2, ib2, A);

    for (int l = 0; l < 4; l++) {
        k_F1g<<<BD * HD, 256, 0, stream>>>(A, inp, ew1, eb1, ew2, eb2, Twig, Y1U);
        k_F2<<<200, 256, 0, stream>>>(Y1U, Y2);
        k_mix<<<400, 256, 0, stream>>>(Y2, Z, fw1, fw2, l);
        k_I1<<<2400, 256, 0, stream>>>(Z, Y1U);
        k_I2<<<BD * HD, 256, 0, stream>>>(Y1U, A, cw, cb, l, (l < 3) ? 1 : 0);
    }
    k_out<<<1800, 256, 0, stream>>>(A, inp, src, pw1, pb1, pw2, pb2, mw, mb,
                                    (float*)d_out);
}

// Round 6
// 724.427 us; speedup vs baseline: 3.2731x; 1.9436x over previous
//
#include <hip/hip_runtime.h>
#include <hip/hip_bf16.h>

#define BD 2
#define HD 480
#define WD 480
#define CD 32
#define HALFD 16
#define WND 20
#define NP 500
#define PLANE (HD*WD)
#define TWO_PI_OVER_NP 0.012566370614359172954f  /* 2*pi/500 */

typedef __attribute__((ext_vector_type(8))) short bf16x8;
typedef __attribute__((ext_vector_type(4))) float f32x4;

__device__ __forceinline__ float gelu_f(float x) {
    return 0.5f * x * (1.0f + erff(x * 0.70710678118654752f));
}

// Input MLP for a: MLP 5->16->32 on (src, grid). Channel-planar bf16 (B,C,H,W).
__global__ void __launch_bounds__(256) k_ae(
    const float* src,
    const float* iw1, const float* ib1,
    const float* iw2, const float* ib2,
    __hip_bfloat16* A)
{
    __shared__ float s_iw1[80], s_ib1[16], s_iw2[512], s_ib2[32];
    int tid = threadIdx.x;
    for (int t = tid; t < 512; t += 256) s_iw2[t] = iw2[t];
    if (tid < 80) s_iw1[tid] = iw1[tid];
    if (tid >= 96 && tid < 112) s_ib1[tid - 96] = ib1[tid - 96];
    if (tid >= 128 && tid < 160) s_ib2[tid - 128] = ib2[tid - 128];
    __syncthreads();
    int gid = blockIdx.x * 256 + tid;  // < 460800
    int b = gid / PLANE;
    int r = gid % PLANE;
    int h = r / WD, w = r % WD;
    float gx = (float)h * (1.0f / 479.0f);
    float gy = (float)w * (1.0f / 479.0f);
    float s0 = src[(size_t)gid * 3 + 0];
    float s1 = src[(size_t)gid * 3 + 1];
    float s2 = src[(size_t)gid * 3 + 2];
    float hid[16];
    #pragma unroll
    for (int j = 0; j < 16; j++) {
        float v = s_ib1[j] + s0 * s_iw1[j] + s1 * s_iw1[16 + j] + s2 * s_iw1[32 + j]
                + gx * s_iw1[48 + j] + gy * s_iw1[64 + j];
        hid[j] = gelu_f(v);
    }
    __hip_bfloat16* Ap = A + (size_t)b * CD * PLANE + r;
    for (int c = 0; c < 32; c++) {
        float v = s_ib2[c];
        #pragma unroll
        for (int j = 0; j < 16; j++) v += hid[j] * s_iw2[j * 32 + c];
        Ap[(size_t)c * PLANE] = __float2bfloat16(v);
    }
}

// Swizzled bf16 twiddle fragments for the F1 row-DFT GEMM.
// B[k=w][n], n = ky*2+part (part0=cos, part1=-sin), n in [0,40) (pad to 48).
// Tile (kt 0..14, nt 0..2): element (lane,j) = B[kt*32+(lane>>4)*8+j][nt*16+(lane&15)].
__global__ void k_twig(__hip_bfloat16* Twig) {
    int e = blockIdx.x * 256 + threadIdx.x;   // < 45*512 = 23040
    if (e >= 45 * 512) return;
    int tile = e >> 9, r = e & 511;
    int lane = r >> 3, j = r & 7;
    int kt = tile / 3, nt = tile % 3;
    int k = kt * 32 + ((lane >> 4) << 3) + j;
    int n = nt * 16 + (lane & 15);
    float v = 0.0f;
    if (n < 40) {
        int ky = n >> 1;
        int idx = (k * ky) % NP;
        float ang = (float)idx * TWO_PI_OVER_NP;
        v = (n & 1) ? -sinf(ang) : cosf(ang);
    }
    Twig[e] = __float2bfloat16(v);
}

// Swizzled bf16 inverse-twiddle B-fragments for the I2 GEMM.
// B[kk][w]: kk = ky*2+part (part0=cos(2pi ky w/500), part1=-sin), kk in [0,40)
// padded to 64. Tile (nt 0..29, kt 0..1) at offset (nt*2+kt)*512:
// element (lane,j) = B[kt*32+(lane>>4)*8+j][nt*16+(lane&15)].
__global__ void k_tinv(__hip_bfloat16* TinvF) {
    int e = blockIdx.x * 256 + threadIdx.x;   // < 60*512 = 30720
    if (e >= 60 * 512) return;
    int tile = e >> 9, r = e & 511;
    int lane = r >> 3, j = r & 7;
    int nt = tile >> 1, kt = tile & 1;
    int kk = kt * 32 + ((lane >> 4) << 3) + j;
    int w = nt * 16 + (lane & 15);
    float v = 0.0f;
    if (kk < 40) {
        int ky = kk >> 1;
        int idx = (ky * w) % NP;
        float ang = (float)idx * TWO_PI_OVER_NP;
        v = (kk & 1) ? -sinf(ang) : cosf(ang);
    }
    TinvF[e] = __float2bfloat16(v);
}

// F1: one block per (b,h) row. Phase 1: recompute e-MLP once per pixel and
// stage g = a*e as bf16 in LDS G[32][488]. Phase 2: row-DFT over w as MFMA
// GEMM (M=32 c, N=48 ky-part padded, K=480 w) against swizzled Twig.
__global__ void __launch_bounds__(256) k_F1g(
    const __hip_bfloat16* A, const float* inp,
    const float* ew1, const float* eb1,
    const float* ew2, const float* eb2,
    const __hip_bfloat16* Twig,
    __hip_bfloat16* Y1)
{
    __shared__ __hip_bfloat16 G[32][488];   // pitch 488: 2-way bank aliasing only
    __shared__ float s_ew1[48], s_eb1[16], s_ew2[512], s_eb2[32];
    int tid = threadIdx.x;
    for (int t = tid; t < 512; t += 256) s_ew2[t] = ew2[t];
    if (tid < 48) s_ew1[tid] = ew1[tid];
    if (tid >= 64 && tid < 80) s_eb1[tid - 64] = eb1[tid - 64];
    if (tid >= 96 && tid < 128) s_eb2[tid - 96] = eb2[tid - 96];
    __syncthreads();
    int b = blockIdx.x / HD;
    int h = blockIdx.x % HD;
    float gx = (float)h * (1.0f / 479.0f);
    const __hip_bfloat16* Abase = A + ((size_t)b * CD) * PLANE + (size_t)h * WD;
    for (int w = tid; w < WD; w += 256) {
        float xi = inp[(size_t)b * PLANE + (size_t)h * WD + w];
        float gy = (float)w * (1.0f / 479.0f);
        float hid[16];
        #pragma unroll
        for (int j = 0; j < 16; j++) {
            float v = s_eb1[j] + xi * s_ew1[j] + gx * s_ew1[16 + j] + gy * s_ew1[32 + j];
            hid[j] = gelu_f(v);
        }
        #pragma unroll
        for (int c = 0; c < 32; c++) {
            float e = s_eb2[c];
            #pragma unroll
            for (int j = 0; j < 16; j++) e += hid[j] * s_ew2[j * 32 + c];
            float a = __bfloat162float(Abase[(size_t)c * PLANE + w]);
            G[c][w] = __float2bfloat16(e * a);
        }
    }
    __syncthreads();
    int wv = tid >> 6, lane = tid & 63;
    int arow_lo = lane & 15;
    int kofs = (lane >> 4) << 3;
    for (int t = wv; t < 6; t += 4) {
        int mt = t & 1, nt = t >> 1;
        f32x4 acc = {0.f, 0.f, 0.f, 0.f};
        int arow = mt * 16 + arow_lo;
        #pragma unroll
        for (int kt = 0; kt < 15; kt++) {
            bf16x8 av = *reinterpret_cast<const bf16x8*>(&G[arow][kt * 32 + kofs]);
            bf16x8 bv = *reinterpret_cast<const bf16x8*>(Twig + (((kt * 3 + nt) << 9) + lane * 8));
            acc = __builtin_amdgcn_mfma_f32_16x16x32_bf16(av, bv, acc, 0, 0, 0);
        }
        int n = nt * 16 + (lane & 15);
        if (n < 40) {
            int ky = n >> 1, part = n & 1;
            int crow = mt * 16 + ((lane >> 4) << 2);
            #pragma unroll
            for (int r = 0; r < 4; r++) {
                int c = crow + r;
                Y1[((((size_t)(b * 32 + c)) * WND + ky) * HD + h) * 2 + part] =
                    __float2bfloat16(acc[r]);
            }
        }
    }
}

// F2: DFT over h for the 40 needed kx. Y2[b,c,ky,kxi] complex fp32.
__global__ void __launch_bounds__(256) k_F2(
    const __hip_bfloat16* Y1, float* Y2)
{
    __shared__ float sC[NP], sS[NP];
    int tid = threadIdx.x;
    for (int t = tid; t < NP; t += 256) {
        float ang = (float)t * TWO_PI_OVER_NP;
        sC[t] = cosf(ang);
        sS[t] = sinf(ang);
    }
    __syncthreads();
    int gid = blockIdx.x * 256 + tid;   // < 51200
    int kxi = gid % 40;
    int ky = (gid / 40) % 20;
    int bc = gid / 800;
    int kx = (kxi < 20) ? kxi : kxi + 460;
    const __hip_bfloat162* y1 = reinterpret_cast<const __hip_bfloat162*>(Y1)
                                + (size_t)bc * WND * HD + (size_t)ky * HD;
    int idx = 0;
    float ar = 0.f, ai = 0.f;
    for (int hh = 0; hh < HD; hh++) {
        __hip_bfloat162 y = y1[hh];
        float yr = __bfloat162float(y.x), yi = __bfloat162float(y.y);
        float cv = sC[idx], sv = sS[idx];
        ar += yr * cv + yi * sv;
        ai += yi * cv - yr * sv;
        idx += kx;
        if (idx >= NP) idx -= NP;
    }
    reinterpret_cast<float2*>(Y2)[((size_t)bc * WND + ky) * 40 + kxi] = make_float2(ar, ai);
}

// Per-frequency channel mixing (real and imag independently).
__global__ void __launch_bounds__(256) k_mix(
    const float* Y2, float* Z,
    const float* fw1, const float* fw2, int l)
{
    int gid = blockIdx.x * 256 + threadIdx.x;  // < 102400
    int z = gid & 1;
    int kxi = (gid >> 1) % 40;
    int ky = (gid / 80) % 20;
    int oc = (gid / 1600) % 32;
    int b = gid / 51200;
    const float* wp;
    int x;
    if (kxi < 20) { wp = fw1; x = kxi; } else { wp = fw2; x = kxi - 20; }
    size_t wbase = ((((size_t)(l * 32) * 32 + oc) * 20 + x) * 20 + ky) * 2 + z;
    const float* y2 = Y2 + (((size_t)b * 32 * 20 + ky) * 40 + kxi) * 2 + z;
    float acc = 0.f;
    for (int i = 0; i < 32; i++) {
        float yv = y2[(size_t)i * 1600];
        float wv = wp[wbase + (size_t)i * 25600];
        acc += yv * wv;
    }
    Z[((((size_t)b * 32 + oc) * 20 + ky) * 40 + kxi) * 2 + z] = acc;
}

// I1: inverse complex DFT over kx -> h. U[b,o,ky,h] complex bf16 (unscaled).
__global__ void __launch_bounds__(256) k_I1(
    const float* Z, __hip_bfloat16* U)
{
    __shared__ float sC[NP], sS[NP];
    int tid = threadIdx.x;
    for (int t = tid; t < NP; t += 256) {
        float ang = (float)t * TWO_PI_OVER_NP;
        sC[t] = cosf(ang);
        sS[t] = sinf(ang);
    }
    __syncthreads();
    int gid = blockIdx.x * 256 + tid;  // < 614400
    int h = gid % HD;
    int ky = (gid / HD) % 20;
    int bo = gid / (HD * 20);   // b*32+oc
    const float2* zp = reinterpret_cast<const float2*>(Z) + ((size_t)bo * WND + ky) * 40;
    float ar = 0.f, ai = 0.f;
    int idx = 0;
    #pragma unroll
    for (int j = 0; j < 20; j++) {
        float2 zz = zp[j];
        float cv = sC[idx], sv = sS[idx];
        ar += zz.x * cv - zz.y * sv;
        ai += zz.x * sv + zz.y * cv;
        idx += h; if (idx >= NP) idx -= NP;
    }
    idx = (480 * h) % NP;
    #pragma unroll
    for (int j = 20; j < 40; j++) {
        float2 zz = zp[j];
        float cv = sC[idx], sv = sS[idx];
        ar += zz.x * cv - zz.y * sv;
        ai += zz.x * sv + zz.y * cv;
        idx += h; if (idx >= NP) idx -= NP;
    }
    __hip_bfloat162 v;
    v.x = __float2bfloat16(ar);
    v.y = __float2bfloat16(ai);
    reinterpret_cast<__hip_bfloat162*>(U)[((size_t)bo * WND + ky) * HD + h] = v;
}

// I2: fused (inverse ky-DFT + 1x1 conv + bias + gelu) as one MFMA GEMM:
//   Anew[oc][w] = act( sum_kk sU[oc][kk]*Tinv[kk][w] + sum_ic W[oc][ic]*Ain[ic][w] + b[oc] )
// M=32 (oc), N=480 (w), K = 64 (DFT, padded from 40) + 32 (conv).
// One block per (b,h). Phase 1 stages all operands in fragment-linear LDS
// (Ain fully read BEFORE the barrier -> in-place A update stays race-free).
__global__ void __launch_bounds__(256) k_I2(
    const __hip_bfloat16* U, __hip_bfloat16* A,
    const float* convw, const float* convb,
    const __hip_bfloat16* TinvF,
    int l, int do_gelu)
{
    __shared__ __align__(16) __hip_bfloat16 sBf[30 * 512];  // Ain B-frags, 30720 B
    __shared__ __align__(16) __hip_bfloat16 sUf[4 * 512];   // U A-frags (mt,kt)
    __shared__ __align__(16) __hip_bfloat16 sWf[2 * 512];   // conv-W A-frags (mt)
    __shared__ float sB[CD];
    int tid = threadIdx.x;
    int b = blockIdx.x / HD;
    int h = blockIdx.x % HD;
    if (tid < CD) sB[tid] = convb[l * CD + tid];
    // U A-fragments: element (mt,kt,lane,j) = sU[mt*16+(lane&15)][kt*32+(lane>>4)*8+j]
    for (int t = tid; t < 2048; t += 256) {
        int j = t & 7, lane = (t >> 3) & 63, ktmt = t >> 9;
        int mt = ktmt >> 1, kt = ktmt & 1;
        int oc = mt * 16 + (lane & 15);
        int kk = kt * 32 + ((lane >> 4) << 3) + j;
        float v = 0.f;
        if (kk < 40) {
            int ky = kk >> 1;
            __hip_bfloat162 u = reinterpret_cast<const __hip_bfloat162*>(U)
                [(((size_t)b * CD + oc) * WND + ky) * HD + h];
            float sc = (ky == 0 ? 1.0f : 2.0f) * (1.0f / 250000.0f);
            v = ((kk & 1) ? __bfloat162float(u.y) : __bfloat162float(u.x)) * sc;
        }
        sUf[t] = __float2bfloat16(v);
    }
    // conv-W A-fragments
    for (int t = tid; t < 1024; t += 256) {
        int j = t & 7, lane = (t >> 3) & 63, mt = t >> 9;
        int oc = mt * 16 + (lane & 15);
        int ic = ((lane >> 4) << 3) + j;
        sWf[t] = __float2bfloat16(convw[(size_t)l * CD * CD + oc * CD + ic]);
    }
    // Ain B-fragments: thread per w holds all 32 ic (coalesced loads per ic),
    // writes 4 x 16B fragment rows: tile nt=w>>4, lane=(q<<4)|(w&15), j=ic&7.
    {
        const unsigned short* Ab = reinterpret_cast<const unsigned short*>(
            A + (size_t)b * CD * PLANE + (size_t)h * WD);
        for (int w = tid; w < WD; w += 256) {
            unsigned short vals[32];
            #pragma unroll
            for (int ic = 0; ic < 32; ic++)
                vals[ic] = Ab[(size_t)ic * PLANE + w];
            int nt = w >> 4, lw = w & 15;
            #pragma unroll
            for (int q = 0; q < 4; q++) {
                uint4 pk;
                pk.x = (unsigned)vals[8 * q + 0] | ((unsigned)vals[8 * q + 1] << 16);
                pk.y = (unsigned)vals[8 * q + 2] | ((unsigned)vals[8 * q + 3] << 16);
                pk.z = (unsigned)vals[8 * q + 4] | ((unsigned)vals[8 * q + 5] << 16);
                pk.w = (unsigned)vals[8 * q + 6] | ((unsigned)vals[8 * q + 7] << 16);
                *reinterpret_cast<uint4*>(&sBf[(nt << 9) + (((q << 4) | lw) << 3)]) = pk;
            }
        }
    }
    __syncthreads();
    int wv = tid >> 6, lane = tid & 63;
    for (int t = wv; t < 60; t += 4) {
        int mt = t & 1, nt = t >> 1;
        f32x4 acc = {0.f, 0.f, 0.f, 0.f};
        #pragma unroll
        for (int kt = 0; kt < 2; kt++) {
            bf16x8 av = *reinterpret_cast<const bf16x8*>(&sUf[((mt * 2 + kt) << 9) + lane * 8]);
            bf16x8 bv = *reinterpret_cast<const bf16x8*>(TinvF + (((nt * 2 + kt) << 9) + lane * 8));
            acc = __builtin_amdgcn_mfma_f32_16x16x32_bf16(av, bv, acc, 0, 0, 0);
        }
        bf16x8 av2 = *reinterpret_cast<const bf16x8*>(&sWf[(mt << 9) + lane * 8]);
        bf16x8 bv2 = *reinterpret_cast<const bf16x8*>(&sBf[(nt << 9) + lane * 8]);
        acc = __builtin_amdgcn_mfma_f32_16x16x32_bf16(av2, bv2, acc, 0, 0, 0);
        int w = nt * 16 + (lane & 15);
        int ocb = mt * 16 + ((lane >> 4) << 2);
        #pragma unroll
        for (int r = 0; r < 4; r++) {
            float v = acc[r] + sB[ocb + r];
            if (do_gelu) v = gelu_f(v);
            A[((size_t)b * CD + (ocb + r)) * PLANE + (size_t)h * WD + w] = __float2bfloat16(v);
        }
    }
}

// Final: proj MLP + 3x3 mask conv (XLA conv = correlation) + field*mask + pred.
__global__ void __launch_bounds__(256) k_out(
    const __hip_bfloat16* Afin, const float* inp, const float* src,
    const float* pw1, const float* pb1,
    const float* pw2, const float* pb2,
    const float* mw, const float* mb,
    float* out)
{
    __shared__ float sW1[CD * HALFD], sB1[HALFD], sW2[HALFD * 2], sB2[2], sM[9], sMB[1];
    int tid = threadIdx.x;
    for (int t = tid; t < CD * HALFD; t += 256) sW1[t] = pw1[t];
    if (tid < 16) sB1[tid] = pb1[tid];
    if (tid >= 32 && tid < 64) sW2[tid - 32] = pw2[tid - 32];
    if (tid >= 64 && tid < 66) sB2[tid - 64] = pb2[tid - 64];
    if (tid >= 96 && tid < 105) sM[tid - 96] = mw[tid - 96];
    if (tid == 128) sMB[0] = mb[0];
    __syncthreads();
    int gid = blockIdx.x * 256 + tid;  // < 460800
    int b = gid / PLANE;
    int r = gid % PLANE;
    int h = r / WD, w = r % WD;
    const __hip_bfloat16* ap = Afin + (size_t)b * CD * PLANE + r;
    float av[32];
    #pragma unroll
    for (int i = 0; i < 32; i++) av[i] = __bfloat162float(ap[(size_t)i * PLANE]);
    float hid[16];
    #pragma unroll
    for (int j = 0; j < 16; j++) {
        float v = sB1[j];
        #pragma unroll
        for (int i = 0; i < 32; i++) v += av[i] * sW1[i * 16 + j];
        hid[j] = gelu_f(v);
    }
    float p0 = sB2[0], p1 = sB2[1];
    #pragma unroll
    for (int j = 0; j < 16; j++) { p0 += hid[j] * sW2[j * 2]; p1 += hid[j] * sW2[j * 2 + 1]; }
    float m = sMB[0];
    #pragma unroll
    for (int dh = 0; dh < 3; dh++) {
        int hh = h + dh - 1;
        #pragma unroll
        for (int dw = 0; dw < 3; dw++) {
            int ww = w + dw - 1;
            if (hh >= 0 && hh < HD && ww >= 0 && ww < WD)
                m += inp[(size_t)b * PLANE + (size_t)hh * WD + ww] * sM[dh * 3 + dw];
        }
    }
    float f0 = src[(size_t)gid * 3 + 1];
    float f1 = src[(size_t)gid * 3 + 2];
    out[(size_t)gid * 2 + 0] = f0 * m + p0;
    out[(size_t)gid * 2 + 1] = f1 * m + p1;
}

extern "C" void kernel_launch(void* const* d_in, const int* in_sizes, int n_in,
                              void* d_out, int out_size, void* d_ws, size_t ws_size,
                              hipStream_t stream) {
    const float* inp = (const float*)d_in[0];
    const float* src = (const float*)d_in[1];
    const float* iw1 = (const float*)d_in[2];
    const float* ib1 = (const float*)d_in[3];
    const float* iw2 = (const float*)d_in[4];
    const float* ib2 = (const float*)d_in[5];
    const float* ew1 = (const float*)d_in[6];
    const float* eb1 = (const float*)d_in[7];
    const float* ew2 = (const float*)d_in[8];
    const float* eb2 = (const float*)d_in[9];
    const float* fw1 = (const float*)d_in[10];
    const float* fw2 = (const float*)d_in[11];
    const float* cw  = (const float*)d_in[12];
    const float* cb  = (const float*)d_in[13];
    const float* pw1 = (const float*)d_in[14];
    const float* pb1 = (const float*)d_in[15];
    const float* pw2 = (const float*)d_in[16];
    const float* pb2 = (const float*)d_in[17];
    const float* mw  = (const float*)d_in[18];
    const float* mb  = (const float*)d_in[19];

    // Workspace layout — total ~32.9 MB:
    //   A     bf16  [64][480][480]        29,491,200 B   layer state, in-place
    //   Y1U   bf16  [64][20][480]x2        2,457,600 B   Y1 (F1->F2) aliased with U (I1->I2)
    //   Y2    fp32  [64][20][40]x2           409,600 B
    //   Z     fp32  [64][20][40]x2           409,600 B
    //   Twig  bf16  45 tiles x 512            46,080 B   F1 DFT B-fragments
    //   TinvF bf16  60 tiles x 512            61,440 B   I2 inverse-DFT B-fragments
    const size_t NA = (size_t)BD * CD * PLANE;          // 14,745,600 elems
    __hip_bfloat16* A   = (__hip_bfloat16*)d_ws;
    __hip_bfloat16* Y1U = A + NA;
    float* Y2 = (float*)(Y1U + (size_t)BD * CD * WND * HD * 2);
    float* Z  = Y2 + (size_t)BD * CD * WND * 40 * 2;
    __hip_bfloat16* Twig  = (__hip_bfloat16*)(Z + (size_t)BD * CD * WND * 40 * 2);
    __hip_bfloat16* TinvF = Twig + 45 * 512;

    k_twig<<<90, 256, 0, stream>>>(Twig);
    k_tinv<<<120, 256, 0, stream>>>(TinvF);
    k_ae<<<1800, 256, 0, stream>>>(src, iw1, ib1, iw2, ib2, A);

    for (int l = 0; l < 4; l++) {
        k_F1g<<<BD * HD, 256, 0, stream>>>(A, inp, ew1, eb1, ew2, eb2, Twig, Y1U);
        k_F2<<<200, 256, 0, stream>>>(Y1U, Y2);
        k_mix<<<400, 256, 0, stream>>>(Y2, Z, fw1, fw2, l);
        k_I1<<<2400, 256, 0, stream>>>(Z, Y1U);
        k_I2<<<BD * HD, 256, 0, stream>>>(Y1U, A, cw, cb, TinvF, l, (l < 3) ? 1 : 0);
    }
    k_out<<<1800, 256, 0, stream>>>(A, inp, src, pw1, pb1, pw2, pb2, mw, mb,
                                    (float*)d_out);
}